// Round 3
// baseline (4306.102 us; speedup 1.0000x reference)
//
#include <hip/hip_runtime.h>
#include <hip/hip_bf16.h>
#include <hip/hip_fp16.h>

// ---------------------------------------------------------------------------
// 3-layer GRU (Keras v2, reset_after=True), B=64 T=2048 F=H=128, OUT=5.
// Round 9: WG-LEVEL PRODUCER/CONSUMER SPLIT (projection on its own CUs).
//   Post-mortems: r7 (wave-split, shared WG barrier) -> lockstep, regressed.
//   r8 (batch-pair ILP, 96 WGs) -> per-CU busy rose to ~69% but CU count
//   halved, regressed. => keep the r6 rec structure on 192 WGs/CUs, move the
//   input projection to 64 DEDICATED proj WGs on the otherwise-idle CUs.
//   No shared barriers (fixes r7); no rec-CU loss (fixes r8).
//   Proj WG b computes xw = in @ K + biases for all 3 layers of batch b into
//   a 4-chunk f32 ring in ws; rec WGs stage ring chunks into LDS (prefetch 1
//   chunk ahead) and run the bare recurrence (~82 instr/step vs ~160 in r6).
//   Flags: hflag[3][64] rec progress (sentinel 1 after prologue staging,
//   c*CHK at chunk c start, T at end); pflag[3][64] proj progress.
//   Deadlock-free: proj waits only on hflags, rec waits only on pflags;
//   if proj ring-blocked at chunk i, rec is provably unblocked (produced
//   through i-1 >= its staging need).
// ws: 3 h-planes f16 (100.7MB) + xw ring f32 (18.9MB) + 384 flags.
// ---------------------------------------------------------------------------

#define HID   128
#define H3    384
#define OUTD  5
#define CHK   16            // steps per chunk (publish/poll granularity)
#define RING  4             // xw ring depth in chunks (per layer,batch)
#define NREC  192           // rec WGs (3 layers x 64 batches)

typedef _Float16 f16x2 __attribute__((ext_vector_type(2)));
typedef _Float16 f16x4 __attribute__((ext_vector_type(4)));
typedef _Float16 f16x8 __attribute__((ext_vector_type(8)));

__device__ __forceinline__ float fdot2(f16x2 a, f16x2 b, float c) {
#if __has_builtin(__builtin_amdgcn_fdot2)
    return __builtin_amdgcn_fdot2(a, b, c, false);   // v_dot2_f32_f16
#else
    return fmaf((float)a.x, (float)b.x, fmaf((float)a.y, (float)b.y, c));
#endif
}

__device__ __forceinline__ float fexp2(float x) {
#if __has_builtin(__builtin_amdgcn_exp2f)
    return __builtin_amdgcn_exp2f(x);
#else
    return exp2f(x);
#endif
}

__device__ __forceinline__ float frcp(float x) {
#if __has_builtin(__builtin_amdgcn_rcpf)
    return __builtin_amdgcn_rcpf(x);
#else
    return 1.f / x;
#endif
}

__device__ __forceinline__ float fsigmoid(float x) {
    return frcp(1.f + fexp2(x * -1.4426950408889634f));
}

__device__ __forceinline__ float ftanh_(float x) {
    return fmaf(-2.f, frcp(1.f + fexp2(x * 2.8853900817779268f)), 1.f);
}

// barrier that does NOT drain vmcnt (unlike __syncthreads): LDS handoff only.
__device__ __forceinline__ void soft_barrier() {
    asm volatile("s_waitcnt lgkmcnt(0)\n\ts_barrier" ::: "memory");
}

// butterfly sum over the kh quad (lanes xor 1, xor 2) on the VALU pipe
__device__ __forceinline__ float quad_sum(float x) {
#if __has_builtin(__builtin_amdgcn_mov_dpp)
    int i1 = __builtin_amdgcn_mov_dpp(__float_as_int(x), 0xB1, 0xF, 0xF, true); // [1,0,3,2]
    x += __int_as_float(i1);
    int i2 = __builtin_amdgcn_mov_dpp(__float_as_int(x), 0x4E, 0xF, 0xF, true); // [2,3,0,1]
    x += __int_as_float(i2);
#else
    x += __shfl_xor(x, 1);
    x += __shfl_xor(x, 2);
#endif
    return x;
}

// ---------------------------------------------------------------------------
__global__ void zero_flags(int* f) {
    if (threadIdx.x < 384) f[threadIdx.x] = 0;
}

// ---------------------------------------------------------------------------
// gru_pipe: 256 WGs, 512 thr.
//  blk <  192: REC role. layer = blk>>6, b = blk&63. Bare recurrence:
//    per step: 3 ds_read_b32 (xw from staged ring chunk) + 4 ds_read_b128 (h)
//    + 48 fdot2 + DPP reduce + gates + h store. xw ring chunk prefetched
//    (global loads at chunk start, LDS write at ts==7).
//  blk >= 192: PROJ role. b = blk-192. Per iteration i: produce xw0[i] (from
//    x), xw1[i-2] (from h0), xw2[i-4] (from h1), 2-row-interleaved fdot2,
//    f32 writes into the ring, pflag release per layer-chunk.
// ---------------------------------------------------------------------------
__global__ __launch_bounds__(512, 2) void gru_pipe(
    const float* __restrict__ x,                         // [64,T,128] fp32
    const float* __restrict__ k0, const float* __restrict__ k1, const float* __restrict__ k2,
    const float* __restrict__ rk0, const float* __restrict__ rk1, const float* __restrict__ rk2,
    const float* __restrict__ b0, const float* __restrict__ b1, const float* __restrict__ b2,
    _Float16* __restrict__ hpl0, _Float16* __restrict__ hpl1, _Float16* __restrict__ hpl2,
    float* __restrict__ xwr,                             // xw ring [3][64][RING][CHK][384] f32
    int* flags, int T)
{
    const int blk = blockIdx.x;
    const int t   = threadIdx.x;      // 0..511
    const int NC  = T / CHK;          // 128 chunks

    __shared__ __align__(16) _Float16 hb[2][HID];        // rec: own-state dbuf
    __shared__ __align__(16) float    xwc[2][CHK][H3];   // rec: staged xw chunks (49KB)
    __shared__ __align__(16) _Float16 ins_p[CHK][HID];   // proj: staged input chunk (4KB)

    if (blk < NREC) {
        // =================== RECURRENT ROLE ====================
        const int layer = blk >> 6;
        const int b     = blk & 63;
        const int j     = t >> 2;         // unit 0..127
        const int kh    = t & 3;          // k-quarter
        const int k0i   = kh * 32;

        const float* Rw = (layer == 0) ? rk0 : (layer == 1) ? rk1 : rk2;
        const float* Bs = (layer == 0) ? b0  : (layer == 1) ? b1  : b2;
        _Float16* hout = (layer == 0) ? hpl0 : (layer == 1) ? hpl1 : hpl2;

        f16x2 wzR[16], wrR[16], whR[16];              // 48 VGPRs
#pragma unroll
        for (int p = 0; p < 16; ++p) {
            const int k = k0i + 2 * p;
            const float* r0p = Rw + (size_t)k * H3;
            const float* r1p = r0p + H3;
            f16x2 a;
            a.x = (_Float16)r0p[j];       a.y = (_Float16)r1p[j];       wzR[p] = a;
            a.x = (_Float16)r0p[j + 128]; a.y = (_Float16)r1p[j + 128]; wrR[p] = a;
            a.x = (_Float16)r0p[j + 256]; a.y = (_Float16)r1p[j + 256]; whR[p] = a;
        }
        const float bhR = Bs[H3 + 256 + j];           // b_rec(h) (inside r*)

        int* hflag = flags + layer * 64 + b;
        int* pflag = flags + NREC + layer * 64 + b;

        _Float16* hob = hout + (size_t)b * T * HID;
        const float* ringb = xwr + (size_t)(layer * 64 + b) * RING * CHK * H3;

        // stage one ring chunk: 16 rows x 384 f32 = 1536 float4; 3/thread.
        float4 sreg[3];
        auto stage_load = [&](int cc) {
            const float* base = ringb + (size_t)(cc & (RING - 1)) * CHK * H3;
#pragma unroll
            for (int i = 0; i < 3; ++i) {
                const int f = t + 512 * i;
                sreg[i] = *(const float4*)(base + 4 * f);
            }
        };
        auto stage_write = [&](int cc) {
            float* dst = &xwc[cc & 1][0][0];
#pragma unroll
            for (int i = 0; i < 3; ++i) {
                const int f = t + 512 * i;
                *(float4*)(dst + 4 * f) = sreg[i];
            }
        };

        if (t < HID) { hb[0][t] = (_Float16)0.f; hb[1][t] = (_Float16)0.f; }

        // ---- prologue: wait xw chunk 0, stage it, publish sentinel ----
        if (t == 0) {
            while (__hip_atomic_load(pflag, __ATOMIC_ACQUIRE, __HIP_MEMORY_SCOPE_AGENT) < CHK)
                __builtin_amdgcn_s_sleep(4);
        }
        __syncthreads();
        stage_load(0);
        stage_write(0);      // vmcnt wait here (prologue only)
        __syncthreads();
        if (t == 0)   // sentinel: chunk 0 staged -> ring slot 0 reusable
            __hip_atomic_store(hflag, 1, __ATOMIC_RELEASE, __HIP_MEMORY_SCOPE_AGENT);

        float h_old = 0.f;
        for (int c = 0; c < NC; ++c) {
            __syncthreads();   // drains vm+lgkm (h stores of prev chunk complete)
            if (t == 0) {
                if (c > 0)
                    __hip_atomic_store(hflag, c * CHK, __ATOMIC_RELEASE, __HIP_MEMORY_SCOPE_AGENT);
                if (c + 1 < NC) {
                    while (__hip_atomic_load(pflag, __ATOMIC_ACQUIRE, __HIP_MEMORY_SCOPE_AGENT) < (c + 2) * CHK)
                        __builtin_amdgcn_s_sleep(4);
                }
            }
            __syncthreads();
            if (c + 1 < NC) stage_load(c + 1);   // in flight ~8 steps before ds_write

            const float* xrow = &xwc[c & 1][0][0];
#pragma unroll 2
            for (int ts = 0; ts < CHK; ++ts) {
                const int tstep = c * CHK + ts;
                const int rbuf  = ts & 1;

                // xw from the staged ring chunk (quad-broadcast ds_read_b32)
                const float xz = xrow[ts * H3 + j];
                const float xr = xrow[ts * H3 + 128 + j];
                const float xh = xrow[ts * H3 + 256 + j];

                // recurrent dot from own h state
                const f16x8* hp = (const f16x8*)(&hb[rbuf][k0i]);
                float sz = 0.f, sr = 0.f, sh = 0.f;
#pragma unroll
                for (int i = 0; i < 4; ++i) {
                    union { f16x8 v; f16x2 p[4]; } u;
                    u.v = hp[i];
#pragma unroll
                    for (int q = 0; q < 4; ++q) {
                        sz = fdot2(u.p[q], wzR[4 * i + q], sz);
                        sr = fdot2(u.p[q], wrR[4 * i + q], sr);
                        sh = fdot2(u.p[q], whR[4 * i + q], sh);
                    }
                }
                sz = quad_sum(sz); sr = quad_sum(sr); sh = quad_sum(sh);

                const float z  = fsigmoid(xz + sz);
                const float r  = fsigmoid(xr + sr);
                const float hh = ftanh_(xh + (sh + bhR) * r);
                const float hn = fmaf(z, h_old - hh, hh);
                h_old = hn;

                if (kh == 0) {
                    hb[rbuf ^ 1][j] = (_Float16)hn;
                    hob[(size_t)tstep * HID + j] = (_Float16)hn;
                }

                if (ts == 7 && c + 1 < NC) stage_write(c + 1);  // vmcnt hidden

                soft_barrier();   // lgkm-only: global loads/stores stay in flight
            }
        }

        __syncthreads();
        if (t == 0)
            __hip_atomic_store(hflag, T, __ATOMIC_RELEASE, __HIP_MEMORY_SCOPE_AGENT);

    } else {
        // =================== PROJECTION ROLE ====================
        const int b   = blk - NREC;       // batch 0..63
        const int j   = t >> 2;           // unit 0..127
        const int kh  = t & 3;            // k-quarter
        const int k0i = kh * 32;

        // resident input weights for ALL 3 layers: 144 f16x2 VGPRs
        f16x2 wK[3][3][16];
        float bzc[3], brc[3], bhc[3];
#pragma unroll
        for (int l = 0; l < 3; ++l) {
            const float* Kl = (l == 0) ? k0 : (l == 1) ? k1 : k2;
            const float* Bl = (l == 0) ? b0 : (l == 1) ? b1 : b2;
#pragma unroll
            for (int p = 0; p < 16; ++p) {
                const int k = k0i + 2 * p;
                const float* c0 = Kl + (size_t)k * H3;
                const float* c1 = c0 + H3;
                f16x2 a;
                a.x = (_Float16)c0[j];       a.y = (_Float16)c1[j];       wK[l][0][p] = a;
                a.x = (_Float16)c0[j + 128]; a.y = (_Float16)c1[j + 128]; wK[l][1][p] = a;
                a.x = (_Float16)c0[j + 256]; a.y = (_Float16)c1[j + 256]; wK[l][2][p] = a;
            }
            bzc[l] = Bl[j]       + Bl[H3 + j];        // b_in(z)+b_rec(z)
            brc[l] = Bl[128 + j] + Bl[H3 + 128 + j];  // b_in(r)+b_rec(r)
            bhc[l] = Bl[256 + j];                     // b_in(h)
        }

        int* hf[3] = { flags + b, flags + 64 + b, flags + 128 + b };
        int* pf[3] = { flags + NREC + b, flags + NREC + 64 + b, flags + NREC + 128 + b };

        const float*    xbp = x    + (size_t)b * T * HID;
        const _Float16* h0b = hpl0 + (size_t)b * T * HID;
        const _Float16* h1b = hpl1 + (size_t)b * T * HID;

        const int row  = t >> 5;          // staging: row 0..15
        const int col4 = (t & 31) * 4;    // staging: 4 f16 per thread

        auto wait_ge = [&](int* f, int v) {
            if (t == 0) {
                while (__hip_atomic_load(f, __ATOMIC_ACQUIRE, __HIP_MEMORY_SCOPE_AGENT) < v)
                    __builtin_amdgcn_s_sleep(4);
            }
            __syncthreads();
        };

        // produce xw for (layer l, chunk cc) into the ring. l is a literal at
        // every call site -> wK indexing stays static after inlining.
        auto do_chunk = [&](int l, int cc) {
            // stage input chunk -> ins_p (f16 [16][128])
            if (l == 0) {
                const float4 v = *(const float4*)(xbp + (size_t)(cc * CHK + row) * HID + col4);
                f16x4 o;
                o[0] = (_Float16)v.x; o[1] = (_Float16)v.y;
                o[2] = (_Float16)v.z; o[3] = (_Float16)v.w;
                *(f16x4*)(&ins_p[row][col4]) = o;
            } else {
                const _Float16* hs = (l == 1) ? h0b : h1b;
                *(f16x4*)(&ins_p[row][col4]) =
                    *(const f16x4*)(hs + (size_t)(cc * CHK + row) * HID + col4);
            }
            __syncthreads();

            float* ring = xwr + ((size_t)(l * 64 + b) * RING + (cc & (RING - 1))) * CHK * H3;
            const float bz = bzc[l], br = brc[l], bh = bhc[l];

#pragma unroll 2
            for (int rp = 0; rp < 8; ++rp) {           // rows 2 at a time (ILP)
                const int r0 = 2 * rp, r1 = r0 + 1;
                const f16x8* p0 = (const f16x8*)(&ins_p[r0][k0i]);
                const f16x8* p1 = (const f16x8*)(&ins_p[r1][k0i]);
                float az0 = 0.f, ar0 = 0.f, ah0 = 0.f;
                float az1 = 0.f, ar1 = 0.f, ah1 = 0.f;
#pragma unroll
                for (int i = 0; i < 4; ++i) {
                    union { f16x8 v; f16x2 p[4]; } u0, u1;
                    u0.v = p0[i]; u1.v = p1[i];
#pragma unroll
                    for (int q = 0; q < 4; ++q) {
                        az0 = fdot2(u0.p[q], wK[l][0][4 * i + q], az0);
                        az1 = fdot2(u1.p[q], wK[l][0][4 * i + q], az1);
                        ar0 = fdot2(u0.p[q], wK[l][1][4 * i + q], ar0);
                        ar1 = fdot2(u1.p[q], wK[l][1][4 * i + q], ar1);
                        ah0 = fdot2(u0.p[q], wK[l][2][4 * i + q], ah0);
                        ah1 = fdot2(u1.p[q], wK[l][2][4 * i + q], ah1);
                    }
                }
                az0 = quad_sum(az0); ar0 = quad_sum(ar0); ah0 = quad_sum(ah0);
                az1 = quad_sum(az1); ar1 = quad_sum(ar1); ah1 = quad_sum(ah1);
                if (kh == 0) {
                    float* o0 = ring + (size_t)r0 * H3;
                    o0[j] = az0 + bz; o0[128 + j] = ar0 + br; o0[256 + j] = ah0 + bh;
                    float* o1 = ring + (size_t)r1 * H3;
                    o1[j] = az1 + bz; o1[128 + j] = ar1 + br; o1[256 + j] = ah1 + bh;
                }
            }
            __syncthreads();   // drains ring stores (vmcnt) before release
            if (t == 0)
                __hip_atomic_store(pf[l], (cc + 1) * CHK, __ATOMIC_RELEASE, __HIP_MEMORY_SCOPE_AGENT);
        };

        // static schedule: iteration i makes xw0[i], xw1[i-2], xw2[i-4].
        for (int i = 0; i < NC + 4; ++i) {
            if (i < NC) {
                // ring backpressure: rec0 must have staged chunk i-RING
                if (i >= RING) wait_ge(hf[0], (i == RING) ? 1 : (i - RING) * CHK);
                do_chunk(0, i);
            }
            if (i >= 2 && i - 2 < NC) {
                const int cc = i - 2;
                wait_ge(hf[0], (cc + 1) * CHK);        // h0 chunk cc complete
                if (cc >= RING) wait_ge(hf[1], (cc == RING) ? 1 : (cc - RING) * CHK);
                do_chunk(1, cc);
            }
            if (i >= 4 && i - 4 < NC) {
                const int cc = i - 4;
                wait_ge(hf[1], (cc + 1) * CHK);        // h1 chunk cc complete
                if (cc >= RING) wait_ge(hf[2], (cc == RING) ? 1 : (cc - RING) * CHK);
                do_chunk(2, cc);
            }
        }
    }
}

// ---------------------------------------------------------------------------
// out_proj: out[r,:] = h_f16[r,:] @ wo + bo (fp32 out). Thread = row.
// ---------------------------------------------------------------------------
__global__ __launch_bounds__(256) void out_proj(
    const _Float16* __restrict__ Hf,  // [R,128] f16
    const float* __restrict__ wo,     // [128,5]
    const float* __restrict__ bo,     // [5]
    float*       __restrict__ out,    // [R,5]
    int R)
{
    const int r = blockIdx.x * 256 + threadIdx.x;
    if (r >= R) return;
    const f16x8* xp = (const f16x8*)(Hf + (size_t)r * HID);

    float a0 = bo[0], a1 = bo[1], a2 = bo[2], a3 = bo[3], a4 = bo[4];
#pragma unroll 4
    for (int c = 0; c < 16; ++c) {
        const f16x8 v = xp[c];
#pragma unroll
        for (int e = 0; e < 8; ++e) {
            const float xv = (float)v[e];
            const float* w = wo + (size_t)(8 * c + e) * OUTD;
            a0 = fmaf(xv, w[0], a0);
            a1 = fmaf(xv, w[1], a1);
            a2 = fmaf(xv, w[2], a2);
            a3 = fmaf(xv, w[3], a3);
            a4 = fmaf(xv, w[4], a4);
        }
    }
    float* op = out + (size_t)r * OUTD;
    op[0] = a0; op[1] = a1; op[2] = a2; op[3] = a3; op[4] = a4;
}

// ---------------------------------------------------------------------------
extern "C" void kernel_launch(void* const* d_in, const int* in_sizes, int n_in,
                              void* d_out, int out_size, void* d_ws, size_t ws_size,
                              hipStream_t stream) {
    const float* x   = (const float*)d_in[0];
    const float* k0  = (const float*)d_in[1];
    const float* rk0 = (const float*)d_in[2];
    const float* b0  = (const float*)d_in[3];
    const float* k1  = (const float*)d_in[4];
    const float* rk1 = (const float*)d_in[5];
    const float* b1  = (const float*)d_in[6];
    const float* k2  = (const float*)d_in[7];
    const float* rk2 = (const float*)d_in[8];
    const float* b2  = (const float*)d_in[9];
    const float* wo  = (const float*)d_in[10];
    const float* bo  = (const float*)d_in[11];
    float* out = (float*)d_out;

    const int BT = in_sizes[0] / HID;   // 64*2048 = 131072 rows
    const int B  = 64;
    const int T  = BT / B;              // 2048

    // ws layout: 3 f16 h-planes + f32 xw ring + flags
    const size_t plane = (size_t)BT * HID * sizeof(_Float16);     // 33.55MB
    const size_t ringb = (size_t)3 * 64 * RING * CHK * H3 * sizeof(float); // 18.87MB
    _Float16* hpl0 = (_Float16*)d_ws;
    _Float16* hpl1 = (_Float16*)((char*)d_ws + plane);
    _Float16* hpl2 = (_Float16*)((char*)d_ws + 2 * plane);
    float*    xwr  = (float*)((char*)d_ws + 3 * plane);
    int*      flags = (int*)((char*)d_ws + 3 * plane + ringb);

    zero_flags<<<1, 512, 0, stream>>>(flags);
    gru_pipe  <<<256, 512, 0, stream>>>(x, k0, k1, k2, rk0, rk1, rk2,
                                        b0, b1, b2, hpl0, hpl1, hpl2, xwr, flags, T);
    out_proj  <<<(BT + 255) / 256, 256, 0, stream>>>(hpl2, wo, bo, out, BT);
}

// Round 4
// 1910.233 us; speedup vs baseline: 2.2542x; 2.2542x over previous
//
#include <hip/hip_runtime.h>
#include <hip/hip_bf16.h>
#include <hip/hip_fp16.h>

// ---------------------------------------------------------------------------
// 3-layer GRU (Keras v2, reset_after=True), B=64 T=2048 F=H=128, OUT=5.
// Round 10: CHUNK-BOUNDARY PROJECTION (r6 shell, proj moved off the step
// critical path).
//   Journal: r6=1752us (best, inline proj, step ~2030cy), r7 wave-split 2038,
//   r8 batch-pair 2941, r9 global-ring 4306. r4/r5 evidence: BARE rec step
//   ~1100cy. Inline proj (+60 instr) costs ~900cy/step because waves are
//   IN-ORDER: proj instrs + their LDS reads extend the per-step dependency
//   chain ~1:1. Same math as a dense per-chunk block is throughput-bound:
//   768 fdot2/thread/chunk ~2000cy => ~125cy/step amortized.
//   Change vs r6 (shell, staging, flags, step math all identical):
//     - per-chunk proj block computes xws[16][384] f32 in LDS (single buf)
//     - step loop reads xz/xr/xh via 3 broadcast ds_read_b32 (as r6 did)
//     - stage_load(c+1) issued BEFORE the proj block: HBM latency hidden
//       under ~2000cy of proj work (better than r6's mid-chunk placement).
// ws: 3 h-planes f16 (~33.5MB each) + 192 flags.
// ---------------------------------------------------------------------------

#define HID   128
#define H3    384
#define OUTD  5
#define CHK   16            // steps per chunk (publish/poll granularity)

typedef _Float16 f16x2 __attribute__((ext_vector_type(2)));
typedef _Float16 f16x8 __attribute__((ext_vector_type(8)));

__device__ __forceinline__ float fdot2(f16x2 a, f16x2 b, float c) {
#if __has_builtin(__builtin_amdgcn_fdot2)
    return __builtin_amdgcn_fdot2(a, b, c, false);   // v_dot2_f32_f16
#else
    return fmaf((float)a.x, (float)b.x, fmaf((float)a.y, (float)b.y, c));
#endif
}

__device__ __forceinline__ float fexp2(float x) {
#if __has_builtin(__builtin_amdgcn_exp2f)
    return __builtin_amdgcn_exp2f(x);
#else
    return exp2f(x);
#endif
}

__device__ __forceinline__ float frcp(float x) {
#if __has_builtin(__builtin_amdgcn_rcpf)
    return __builtin_amdgcn_rcpf(x);
#else
    return 1.f / x;
#endif
}

// sigmoid(x) = 1/(1+exp(-x)); saturates correctly at +-inf.
__device__ __forceinline__ float fsigmoid(float x) {
    return frcp(1.f + fexp2(x * -1.4426950408889634f));
}

// tanh(x) = 1 - 2/(1+exp(2x)); saturates correctly at +-inf.
__device__ __forceinline__ float ftanh_(float x) {
    return fmaf(-2.f, frcp(1.f + fexp2(x * 2.8853900817779268f)), 1.f);
}

// barrier that does NOT drain vmcnt (unlike __syncthreads): LDS handoff only.
__device__ __forceinline__ void soft_barrier() {
    asm volatile("s_waitcnt lgkmcnt(0)\n\ts_barrier" ::: "memory");
}

// butterfly sum over the kh quad (lanes xor 1, xor 2) on the VALU pipe
__device__ __forceinline__ float quad_sum(float x) {
#if __has_builtin(__builtin_amdgcn_mov_dpp)
    int i1 = __builtin_amdgcn_mov_dpp(__float_as_int(x), 0xB1, 0xF, 0xF, true); // [1,0,3,2]
    x += __int_as_float(i1);
    int i2 = __builtin_amdgcn_mov_dpp(__float_as_int(x), 0x4E, 0xF, 0xF, true); // [2,3,0,1]
    x += __int_as_float(i2);
#else
    x += __shfl_xor(x, 1);
    x += __shfl_xor(x, 2);
#endif
    return x;
}

// ---------------------------------------------------------------------------
__global__ void zero_flags(int* f) {
    if (threadIdx.x < 192) f[threadIdx.x] = 0;
}

// ---------------------------------------------------------------------------
// gru_pipe: 192 WGs = 3 layers x 64 batches, 512 thr (8 waves, 2/SIMD).
// Thread (j = t>>2, kh = t&3): unit j, k-quarter kh. Per chunk:
//   [boundary] barrier/flags -> stage_load(c+1) issued -> PROJ BLOCK
//   (xws[16][384] = ins[c&1] @ K + biases, 768 fdot2/thread, 2-row ILP)
//   -> barrier -> 16 bare rec steps (3 b32 xw reads + 48 fdot2 + DPP reduce
//   + gates + h store; stage_write(c+1) at ts==7).
// ---------------------------------------------------------------------------
__global__ __launch_bounds__(512, 2) void gru_pipe(
    const float* __restrict__ x,                         // [64,T,128] fp32
    const float* __restrict__ k0, const float* __restrict__ k1, const float* __restrict__ k2,
    const float* __restrict__ rk0, const float* __restrict__ rk1, const float* __restrict__ rk2,
    const float* __restrict__ b0, const float* __restrict__ b1, const float* __restrict__ b2,
    _Float16* __restrict__ hpl0, _Float16* __restrict__ hpl1, _Float16* __restrict__ hpl2,
    int* flags, int T)
{
    const int blk   = blockIdx.x;
    const int layer = blk >> 6;       // 0..2
    const int b     = blk & 63;       // batch
    const int t     = threadIdx.x;    // 0..511
    const int j     = t >> 2;         // unit 0..127
    const int kh    = t & 3;          // k-quarter
    const int k0i   = kh * 32;
    const int NC    = T / CHK;        // 128 chunks

    const float* Kw = (layer == 0) ? k0  : (layer == 1) ? k1  : k2;
    const float* Rw = (layer == 0) ? rk0 : (layer == 1) ? rk1 : rk2;
    const float* Bs = (layer == 0) ? b0  : (layer == 1) ? b1  : b2;
    const _Float16* hin = (layer == 1) ? hpl0 : hpl1;    // unused for layer 0
    _Float16* hout = (layer == 0) ? hpl0 : (layer == 1) ? hpl1 : hpl2;

    __shared__ __align__(16) _Float16 hb[2][HID];        // own-state dbuf
    __shared__ __align__(16) _Float16 ins[2][CHK][HID];  // staged input rows (8KB)
    __shared__ __align__(16) float    xws[CHK][H3];      // chunk xw buffer (24.5KB)

    // resident weights: recurrent + input, 3 gates x 16 f16x2 each = 96 VGPRs
    f16x2 wzR[16], wrR[16], whR[16], wzK[16], wrK[16], whK[16];
#pragma unroll
    for (int p = 0; p < 16; ++p) {
        const int k = k0i + 2 * p;
        const float* r0p = Rw + (size_t)k * H3;
        const float* r1p = r0p + H3;
        const float* k0p = Kw + (size_t)k * H3;
        const float* k1p = k0p + H3;
        f16x2 a;
        a.x = (_Float16)r0p[j];       a.y = (_Float16)r1p[j];       wzR[p] = a;
        a.x = (_Float16)r0p[j + 128]; a.y = (_Float16)r1p[j + 128]; wrR[p] = a;
        a.x = (_Float16)r0p[j + 256]; a.y = (_Float16)r1p[j + 256]; whR[p] = a;
        a.x = (_Float16)k0p[j];       a.y = (_Float16)k1p[j];       wzK[p] = a;
        a.x = (_Float16)k0p[j + 128]; a.y = (_Float16)k1p[j + 128]; wrK[p] = a;
        a.x = (_Float16)k0p[j + 256]; a.y = (_Float16)k1p[j + 256]; whK[p] = a;
    }
    const float bzK = Bs[j]       + Bs[H3 + j];          // b_in(z)+b_rec(z)
    const float brK = Bs[128 + j] + Bs[H3 + 128 + j];    // b_in(r)+b_rec(r)
    const float bhK = Bs[256 + j];                       // b_in(h)
    const float bhR = Bs[H3 + 256 + j];                  // b_rec(h) (inside r*)

    int* myflag = flags + layer * 64 + b;
    int* sflag  = flags + (layer - 1) * 64 + b;

    const float*    xb  = x    + (size_t)b * T * HID;
    const _Float16* hib = hin  + (size_t)b * T * HID;
    _Float16*       hob = hout + (size_t)b * T * HID;

    // ---- staging helpers: chunk = CHK rows x 128 f16 = 1024 f16x2 dwords ----
    // thread handles 2 dwords: d = t + 512*i -> row = d>>6, col2 = d&63.
    f16x2 sreg[2];
    auto stage_load = [&](int cc) {
#pragma unroll
        for (int i = 0; i < 2; ++i) {
            const int d  = t + 512 * i;
            const int rw = d >> 6;
            const int c2 = d & 63;
            const size_t off = (size_t)(cc * CHK + rw) * HID + 2 * c2;
            if (layer == 0) {
                const float2 v = *(const float2*)(xb + off);
                f16x2 o; o.x = (_Float16)v.x; o.y = (_Float16)v.y;
                sreg[i] = o;
            } else {
                sreg[i] = *(const f16x2*)(hib + off);
            }
        }
    };
    auto stage_write = [&](int cc) {
        const int slot = cc & 1;
#pragma unroll
        for (int i = 0; i < 2; ++i) {
            const int d  = t + 512 * i;
            const int rw = d >> 6;
            const int c2 = d & 63;
            *(f16x2*)(&ins[slot][rw][2 * c2]) = sreg[i];
        }
    };

    if (t < HID) { hb[0][t] = (_Float16)0.f; hb[1][t] = (_Float16)0.f; }

    // ---- prologue: stage chunk 0 ----
    if (layer > 0 && t == 0) {
        while (__hip_atomic_load(sflag, __ATOMIC_ACQUIRE, __HIP_MEMORY_SCOPE_AGENT) < CHK)
            __builtin_amdgcn_s_sleep(4);
    }
    __syncthreads();
    stage_load(0);
    stage_write(0);      // vmcnt wait here (prologue only)

    float h_old = 0.f;

    // ---- main loop over chunks ----
    for (int c = 0; c < NC; ++c) {
        __syncthreads();   // A: drains vm+lgkm (prev chunk's h stores + staging)
        if (t == 0) {
            if (layer < 2 && c > 0)
                __hip_atomic_store(myflag, c * CHK, __ATOMIC_RELEASE, __HIP_MEMORY_SCOPE_AGENT);
            if (layer > 0 && c + 1 < NC) {
                while (__hip_atomic_load(sflag, __ATOMIC_ACQUIRE, __HIP_MEMORY_SCOPE_AGENT) < (c + 2) * CHK)
                    __builtin_amdgcn_s_sleep(4);
            }
        }
        __syncthreads();   // B
        if (c + 1 < NC) stage_load(c + 1);   // HBM latency hides under proj block

        // ---- proj block: xws[16][384] = ins[c&1] @ K + biases ----
        {
            const _Float16 (*insc)[HID] = ins[c & 1];
#pragma unroll 2
            for (int rp = 0; rp < 8; ++rp) {           // rows 2 at a time (ILP)
                const int r0 = 2 * rp, r1 = r0 + 1;
                const f16x8* p0 = (const f16x8*)(&insc[r0][k0i]);
                const f16x8* p1 = (const f16x8*)(&insc[r1][k0i]);
                float az0 = 0.f, ar0 = 0.f, ah0 = 0.f;
                float az1 = 0.f, ar1 = 0.f, ah1 = 0.f;
#pragma unroll
                for (int i = 0; i < 4; ++i) {
                    union { f16x8 v; f16x2 p[4]; } u0, u1;
                    u0.v = p0[i]; u1.v = p1[i];
#pragma unroll
                    for (int q = 0; q < 4; ++q) {
                        az0 = fdot2(u0.p[q], wzK[4 * i + q], az0);
                        az1 = fdot2(u1.p[q], wzK[4 * i + q], az1);
                        ar0 = fdot2(u0.p[q], wrK[4 * i + q], ar0);
                        ar1 = fdot2(u1.p[q], wrK[4 * i + q], ar1);
                        ah0 = fdot2(u0.p[q], whK[4 * i + q], ah0);
                        ah1 = fdot2(u1.p[q], whK[4 * i + q], ah1);
                    }
                }
                az0 = quad_sum(az0); ar0 = quad_sum(ar0); ah0 = quad_sum(ah0);
                az1 = quad_sum(az1); ar1 = quad_sum(ar1); ah1 = quad_sum(ah1);
                if (kh == 0) {
                    xws[r0][j] = az0 + bzK; xws[r0][128 + j] = ar0 + brK; xws[r0][256 + j] = ah0 + bhK;
                    xws[r1][j] = az1 + bzK; xws[r1][128 + j] = ar1 + brK; xws[r1][256 + j] = ah1 + bhK;
                }
            }
        }
        soft_barrier();    // C: xws visible (lgkm-only; global loads stay in flight)

        // ---- 16 bare rec steps ----
#pragma unroll 2
        for (int ts = 0; ts < CHK; ++ts) {
            const int tstep = c * CHK + ts;
            const int rbuf  = ts & 1;

            // xw from the chunk buffer (quad-broadcast ds_read_b32; latency
            // hides under the fdot chain)
            const float xz = xws[ts][j];
            const float xr = xws[ts][128 + j];
            const float xh = xws[ts][256 + j];

            // recurrent dot from own h state
            const f16x8* hp = (const f16x8*)(&hb[rbuf][k0i]);
            float sz = 0.f, sr = 0.f, sh = 0.f;
#pragma unroll
            for (int i = 0; i < 4; ++i) {
                union { f16x8 v; f16x2 p[4]; } u;
                u.v = hp[i];
#pragma unroll
                for (int q = 0; q < 4; ++q) {
                    sz = fdot2(u.p[q], wzR[4 * i + q], sz);
                    sr = fdot2(u.p[q], wrR[4 * i + q], sr);
                    sh = fdot2(u.p[q], whR[4 * i + q], sh);
                }
            }
            sz = quad_sum(sz); sr = quad_sum(sr); sh = quad_sum(sh);

            const float z  = fsigmoid(xz + sz);
            const float r  = fsigmoid(xr + sr);
            const float hh = ftanh_(xh + (sh + bhR) * r);
            const float hn = fmaf(z, h_old - hh, hh);
            h_old = hn;

            if (kh == 0) {
                hb[rbuf ^ 1][j] = (_Float16)hn;
                hob[(size_t)tstep * HID + j] = (_Float16)hn;
            }

            if (ts == 7 && c + 1 < NC) stage_write(c + 1);  // vmcnt hidden (loads ~1 proj block old)

            soft_barrier();   // lgkm-only: global loads/stores stay in flight
        }
    }

    // final publish
    __syncthreads();
    if (t == 0 && layer < 2)
        __hip_atomic_store(myflag, T, __ATOMIC_RELEASE, __HIP_MEMORY_SCOPE_AGENT);
}

// ---------------------------------------------------------------------------
// out_proj: out[r,:] = h_f16[r,:] @ wo + bo (fp32 out). Thread = row.
// ---------------------------------------------------------------------------
__global__ __launch_bounds__(256) void out_proj(
    const _Float16* __restrict__ Hf,  // [R,128] f16
    const float* __restrict__ wo,     // [128,5]
    const float* __restrict__ bo,     // [5]
    float*       __restrict__ out,    // [R,5]
    int R)
{
    const int r = blockIdx.x * 256 + threadIdx.x;
    if (r >= R) return;
    const f16x8* xp = (const f16x8*)(Hf + (size_t)r * HID);

    float a0 = bo[0], a1 = bo[1], a2 = bo[2], a3 = bo[3], a4 = bo[4];
#pragma unroll 4
    for (int c = 0; c < 16; ++c) {
        const f16x8 v = xp[c];
#pragma unroll
        for (int e = 0; e < 8; ++e) {
            const float xv = (float)v[e];
            const float* w = wo + (size_t)(8 * c + e) * OUTD;
            a0 = fmaf(xv, w[0], a0);
            a1 = fmaf(xv, w[1], a1);
            a2 = fmaf(xv, w[2], a2);
            a3 = fmaf(xv, w[3], a3);
            a4 = fmaf(xv, w[4], a4);
        }
    }
    float* op = out + (size_t)r * OUTD;
    op[0] = a0; op[1] = a1; op[2] = a2; op[3] = a3; op[4] = a4;
}

// ---------------------------------------------------------------------------
extern "C" void kernel_launch(void* const* d_in, const int* in_sizes, int n_in,
                              void* d_out, int out_size, void* d_ws, size_t ws_size,
                              hipStream_t stream) {
    const float* x   = (const float*)d_in[0];
    const float* k0  = (const float*)d_in[1];
    const float* rk0 = (const float*)d_in[2];
    const float* b0  = (const float*)d_in[3];
    const float* k1  = (const float*)d_in[4];
    const float* rk1 = (const float*)d_in[5];
    const float* b1  = (const float*)d_in[6];
    const float* k2  = (const float*)d_in[7];
    const float* rk2 = (const float*)d_in[8];
    const float* b2  = (const float*)d_in[9];
    const float* wo  = (const float*)d_in[10];
    const float* bo  = (const float*)d_in[11];
    float* out = (float*)d_out;

    const int BT = in_sizes[0] / HID;   // 64*2048 = 131072 rows
    const int B  = 64;
    const int T  = BT / B;              // 2048

    // ws layout: 3 f16 h-planes + flags
    const size_t plane = (size_t)BT * HID * sizeof(_Float16);
    _Float16* hpl0 = (_Float16*)d_ws;
    _Float16* hpl1 = (_Float16*)((char*)d_ws + plane);
    _Float16* hpl2 = (_Float16*)((char*)d_ws + 2 * plane);
    int*      flags = (int*)((char*)d_ws + 3 * plane);

    zero_flags<<<1, 256, 0, stream>>>(flags);
    gru_pipe  <<<192, 512, 0, stream>>>(x, k0, k1, k2, rk0, rk1, rk2,
                                        b0, b1, b2, hpl0, hpl1, hpl2, flags, T);
    out_proj  <<<(BT + 255) / 256, 256, 0, stream>>>(hpl2, wo, bo, out, BT);
}